// Round 6
// baseline (455.600 us; speedup 1.0000x reference)
//
#include <hip/hip_runtime.h>

// StandardTrafficCoordinator: B=1024, N=64, F=512, H=512.
// pre = states@(63*W1)^T + Am@(states@W2f^T) + msg_d@W2d^T   (associativity)
// R4: LDS 153.6KB -> ~51KB for 2 blocks/CU (2 waves/SIMD). States staged in
// row-halves [32][520]; C1 result transposed via 1.25KB wave-private scratch
// into registers (afr_reg), killing the 73.7KB U2T buffer.

typedef __attribute__((ext_vector_type(8))) short bf16x8;
typedef __attribute__((ext_vector_type(4))) float f32x4;
typedef __attribute__((ext_vector_type(4))) unsigned short us4;

__device__ __forceinline__ unsigned short f2bf(float x) {
  union { float f; unsigned int u; } c; c.f = x;
  return (unsigned short)((c.u + 0x7FFFu + ((c.u >> 16) & 1u)) >> 16);  // RNE
}

// prep: Wgb[h][k] = bf16((k<512?63:1)*Wg[h][k]); coalesced, 2 floats/thread.
// auxw[h][8] = {63*bg, W2d0, W2d1, W4[0], W4[1], W5, 0, 0}
__global__ __launch_bounds__(256) void prep_kernel(
    const float* __restrict__ Wg, const float* __restrict__ bg,
    const float* __restrict__ W4, const float* __restrict__ W5,
    unsigned short* __restrict__ Wgb, float* __restrict__ auxw)
{
  const int id = blockIdx.x * 256 + threadIdx.x;   // 512*512 threads
  const int h = id >> 9;
  const int kp = id & 511;
  const int k = kp * 2;
  const float* row = Wg + h * 1026;
  const float s = (k < 512) ? 63.0f : 1.0f;
  unsigned int lo = f2bf(s * row[k]);
  unsigned int hi = f2bf(s * row[k + 1]);
  *(unsigned int*)&Wgb[h * 1024 + k] = lo | (hi << 16);
  if (kp == 0) {
    float* a = auxw + h * 8;
    a[0] = 63.0f * bg[h];
    a[1] = row[1024];
    a[2] = row[1025];
    a[3] = W4[h];
    a[4] = W4[512 + h];
    a[5] = W5[h];
    a[6] = 0.0f; a[7] = 0.0f;
  }
}

__global__ __launch_bounds__(256, 2) void traffic_kernel(
    const float* __restrict__ locs, const float* __restrict__ states,
    const unsigned short* __restrict__ Wgb, const float* __restrict__ auxw,
    const float* __restrict__ b4, const float* __restrict__ b5,
    float* __restrict__ out)
{
  __shared__ unsigned short S[32 * 520];     // 32 state rows, bf16, +8 pad (33.3 KB)
  __shared__ unsigned short Am[64 * 72];     // adjacency, diag 0 (9.2 KB)
  __shared__ unsigned short scr[4][16 * 40]; // per-wave transpose scratch (5 KB)
  __shared__ float locs_s[128];
  __shared__ float msgd[128];
  __shared__ float red[4 * 64 * 3];
  // total ~51.2 KB -> 2 blocks/CU (LDS); VGPR capped by launch_bounds(256,2)

  const int t = threadIdx.x;
  const int b = blockIdx.x;
  const int lane = t & 63;
  const int w = t >> 6;
  const int llo = lane & 15;
  const int lhi = lane >> 4;
  const int hw = w * 128;                    // wave's h-slice base

  if (t < 128) locs_s[t] = locs[b * 128 + t];
  __syncthreads();

  // ---- Phase A: adjacency Am + msg_d ----
  {
    const int i = t >> 2;
    const int j0 = (t & 3) * 16;
    const float xi = locs_s[2*i], yi = locs_s[2*i+1];
    float a[16]; float psum = 0.f;
#pragma unroll
    for (int q = 0; q < 16; ++q) {
      int j = j0 + q;
      float dx = xi - locs_s[2*j];
      float dy = yi - locs_s[2*j+1];
      a[q] = (dx*dx + dy*dy < 1.0f) ? 1.0f : 0.0f;
      psum += a[q];
    }
    psum += __shfl_xor(psum, 1);
    psum += __shfl_xor(psum, 2);
    const float inv = 1.0f / psum;
    float m0 = 0.f, m1 = 0.f;
#pragma unroll
    for (int q = 0; q < 16; ++q) {
      int j = j0 + q;
      float v = (j == i) ? 0.f : a[q] * inv;
      a[q] = v;
      m0 += v * (xi - locs_s[2*j]);
      m1 += v * (yi - locs_s[2*j+1]);
    }
    m0 += __shfl_xor(m0, 1); m0 += __shfl_xor(m0, 2);
    m1 += __shfl_xor(m1, 1); m1 += __shfl_xor(m1, 2);
    if ((t & 3) == 0) { msgd[2*i] = m0; msgd[2*i+1] = m1; }
    union { unsigned short h8[8]; uint4 v4; } pk;
#pragma unroll
    for (int q = 0; q < 8; ++q) pk.h8[q] = f2bf(a[q]);
    *(uint4*)&Am[i*72 + j0] = pk.v4;
#pragma unroll
    for (int q = 0; q < 8; ++q) pk.h8[q] = f2bf(a[8+q]);
    *(uint4*)&Am[i*72 + j0 + 8] = pk.v4;
  }

  // ---- staging: 32 state rows (one half) f32 -> S bf16 ----
  auto stageS = [&](int half) {
    const float4* sb = (const float4*)(states + (size_t)b * 32768 + half * 16384);
#pragma unroll
    for (int it = 0; it < 16; ++it) {
      int id = it * 256 + t;
      int j = id >> 7;
      int f0 = (id & 127) * 4;
      float4 v = sb[id];
      us4 s4;
      s4.x = f2bf(v.x); s4.y = f2bf(v.y);
      s4.z = f2bf(v.z); s4.w = f2bf(v.w);
      *(us4*)&S[j * 520 + f0] = s4;
    }
  };

  f32x4 acc[8][4];        // pre^T accumulator [mt(h)][nt(i)]
  bf16x8 afr_reg[8];      // U2 A-fragments for D' (from transpose)
  unsigned short* sc = &scr[w][0];
  const size_t wb = (size_t)(hw + llo) * 1024 + lhi * 8;  // Wgb lane base

  // C1 chunk: au = W2f(4 mt rows) x S-half; transpose -> afr_reg[c*4..c*4+3]
  auto c1_chunk = [&](int c) {
    f32x4 au[4][2];
#pragma unroll
    for (int m = 0; m < 4; ++m)
#pragma unroll
      for (int n = 0; n < 2; ++n) au[m][n] = f32x4{0.f,0.f,0.f,0.f};
#pragma unroll 4
    for (int ks = 0; ks < 16; ++ks) {
      bf16x8 afr[4], bfr[2];
#pragma unroll
      for (int m = 0; m < 4; ++m)
        afr[m] = *(const bf16x8*)&Wgb[wb + (size_t)(c*4+m)*16384 + 512 + ks*32];
#pragma unroll
      for (int n = 0; n < 2; ++n)
        bfr[n] = *(const bf16x8*)&S[(n*16 + llo)*520 + ks*32 + lhi*8];
#pragma unroll
      for (int m = 0; m < 4; ++m)
#pragma unroll
        for (int n = 0; n < 2; ++n)
          au[m][n] = __builtin_amdgcn_mfma_f32_16x16x32_bf16(afr[m], bfr[n], au[m][n], 0, 0, 0);
    }
    // per-mt transpose: C-layout (row=lhi*4+r, col=llo) -> A-frag (row=llo, k=lhi*8..)
#pragma unroll
    for (int m = 0; m < 4; ++m) {
#pragma unroll
      for (int n = 0; n < 2; ++n)
#pragma unroll
        for (int r = 0; r < 4; ++r)
          sc[(lhi*4 + r)*40 + n*16 + llo] = f2bf(au[m][n][r]);
      // same-wave in-order DS pipe: reads see prior writes (validated pattern)
      afr_reg[c*4 + m] = *(const bf16x8*)&sc[llo*40 + lhi*8];
    }
  };

  // D': acc += U2(regs) x Am(cols half*32..half*32+31), K=32
  auto dprime = [&](int half) {
#pragma unroll
    for (int nt = 0; nt < 4; ++nt) {
      bf16x8 bfr = *(const bf16x8*)&Am[(nt*16 + llo)*72 + half*32 + lhi*8];
#pragma unroll
      for (int mt = 0; mt < 8; ++mt)
        acc[mt][nt] = __builtin_amdgcn_mfma_f32_16x16x32_bf16(afr_reg[mt], bfr, acc[mt][nt], 0, 0, 0);
    }
  };

  // C2 half: acc[:, half*2+n] += 63W1 x S-half (full K=512)
  auto c2_half = [&](int half) {
#pragma unroll 4
    for (int ks = 0; ks < 16; ++ks) {
      bf16x8 afr[8], bfr[2];
#pragma unroll
      for (int mt = 0; mt < 8; ++mt)
        afr[mt] = *(const bf16x8*)&Wgb[wb + (size_t)mt*16384 + ks*32];
#pragma unroll
      for (int n = 0; n < 2; ++n)
        bfr[n] = *(const bf16x8*)&S[(n*16 + llo)*520 + ks*32 + lhi*8];
#pragma unroll
      for (int mt = 0; mt < 8; ++mt)
#pragma unroll
        for (int n = 0; n < 2; ++n)
          acc[mt][half*2 + n] = __builtin_amdgcn_mfma_f32_16x16x32_bf16(afr[mt], bfr[n], acc[mt][half*2 + n], 0, 0, 0);
    }
  };

  // ---- half 0 (state rows 0..31) ----
  stageS(0);
  __syncthreads();
  c1_chunk(0); c1_chunk(1);
#pragma unroll
  for (int mt = 0; mt < 8; ++mt)
#pragma unroll
    for (int nt = 0; nt < 4; ++nt) acc[mt][nt] = f32x4{0.f,0.f,0.f,0.f};
  dprime(0);
  c2_half(0);
  __syncthreads();                 // all waves done with S half 0

  // ---- half 1 (state rows 32..63) ----
  stageS(1);
  __syncthreads();
  c1_chunk(0); c1_chunk(1);
  dprime(1);
  c2_half(1);

  // ---- epilogue: + msg_d@W2d + 63bg, relu, project W4/W5 ----
  float mdx[4], mdy[4];
#pragma unroll
  for (int nt = 0; nt < 4; ++nt) {
    mdx[nt] = msgd[2*(nt*16 + llo)];
    mdy[nt] = msgd[2*(nt*16 + llo) + 1];
  }
  float pp0[4] = {0,0,0,0}, pp1[4] = {0,0,0,0}, vv[4] = {0,0,0,0};
#pragma unroll
  for (int mt = 0; mt < 8; ++mt) {
#pragma unroll
    for (int r = 0; r < 4; ++r) {
      int hh = hw + mt*16 + lhi*4 + r;
      float4 ax0 = *(const float4*)&auxw[hh*8];
      float4 ax1 = *(const float4*)&auxw[hh*8 + 4];
#pragma unroll
      for (int nt = 0; nt < 4; ++nt) {
        float val = acc[mt][nt][r] + ax0.x + mdx[nt]*ax0.y + mdy[nt]*ax0.z;
        val = fmaxf(val, 0.f);
        pp0[nt] += val * ax0.w;
        pp1[nt] += val * ax1.x;
        vv[nt]  += val * ax1.y;
      }
    }
  }
#pragma unroll
  for (int nt = 0; nt < 4; ++nt) {
    pp0[nt] += __shfl_xor(pp0[nt], 16); pp0[nt] += __shfl_xor(pp0[nt], 32);
    pp1[nt] += __shfl_xor(pp1[nt], 16); pp1[nt] += __shfl_xor(pp1[nt], 32);
    vv[nt]  += __shfl_xor(vv[nt], 16);  vv[nt]  += __shfl_xor(vv[nt], 32);
  }
  if (lane < 16) {
#pragma unroll
    for (int nt = 0; nt < 4; ++nt) {
      int i = nt*16 + llo;
      red[(w*64 + i)*3 + 0] = pp0[nt];
      red[(w*64 + i)*3 + 1] = pp1[nt];
      red[(w*64 + i)*3 + 2] = vv[nt];
    }
  }
  __syncthreads();
  if (t < 192) {
    int o = t >> 6;                  // 0,1 -> policies; 2 -> values
    int i = t & 63;
    float s = red[(0*64+i)*3+o] + red[(1*64+i)*3+o]
            + red[(2*64+i)*3+o] + red[(3*64+i)*3+o];
    s += (o < 2) ? b4[o] : b5[0];
    if (o < 2) out[((size_t)b*64 + i)*2 + o] = s;
    else       out[(size_t)131072 + (size_t)b*64 + i] = s;
  }
}

extern "C" void kernel_launch(void* const* d_in, const int* in_sizes, int n_in,
                              void* d_out, int out_size, void* d_ws, size_t ws_size,
                              hipStream_t stream)
{
  const float* locs   = (const float*)d_in[0];
  const float* states = (const float*)d_in[1];
  const float* Wg     = (const float*)d_in[2];
  const float* bg     = (const float*)d_in[3];
  const float* W4     = (const float*)d_in[4];
  const float* b4     = (const float*)d_in[5];
  const float* W5     = (const float*)d_in[6];
  const float* b5     = (const float*)d_in[7];

  unsigned short* Wgb = (unsigned short*)d_ws;                   // 1 MB bf16 weights
  float* auxw = (float*)((char*)d_ws + 512 * 1024 * 2);          // 16 KB epilogue table

  prep_kernel<<<1024, 256, 0, stream>>>(Wg, bg, W4, W5, Wgb, auxw);
  traffic_kernel<<<1024, 256, 0, stream>>>(locs, states, Wgb, auxw, b4, b5, (float*)d_out);
}

// Round 10
// 446.182 us; speedup vs baseline: 1.0211x; 1.0211x over previous
//
#include <hip/hip_runtime.h>

// StandardTrafficCoordinator: B=1024, N=64, F=512, H=512.
// pre = states@(63*W1)^T + Am@(states@W2f^T) + msg_d@W2d^T   (associativity)
// R7: R4's 2-blocks/CU goal WITHOUT spills: 512-thread blocks (8 waves),
// wave owns 64 h-rows -> acc[4][4]=64 VGPRs; C1 in 1-mt chunks; true
// per-thread pressure ~116 <= 128 cap. LDS ~60KB -> 2 blocks/CU.

typedef __attribute__((ext_vector_type(8))) short bf16x8;
typedef __attribute__((ext_vector_type(4))) float f32x4;
typedef __attribute__((ext_vector_type(4))) unsigned short us4;

__device__ __forceinline__ unsigned short f2bf(float x) {
  union { float f; unsigned int u; } c; c.f = x;
  return (unsigned short)((c.u + 0x7FFFu + ((c.u >> 16) & 1u)) >> 16);  // RNE
}

// prep: Wgb[h][k] = bf16((k<512?63:1)*Wg[h][k]); coalesced, 2 floats/thread.
// auxw[h][8] = {63*bg, W2d0, W2d1, W4[0], W4[1], W5, 0, 0}
__global__ __launch_bounds__(256) void prep_kernel(
    const float* __restrict__ Wg, const float* __restrict__ bg,
    const float* __restrict__ W4, const float* __restrict__ W5,
    unsigned short* __restrict__ Wgb, float* __restrict__ auxw)
{
  const int id = blockIdx.x * 256 + threadIdx.x;   // 512*512 threads
  const int h = id >> 9;
  const int kp = id & 511;
  const int k = kp * 2;
  const float* row = Wg + h * 1026;
  const float s = (k < 512) ? 63.0f : 1.0f;
  unsigned int lo = f2bf(s * row[k]);
  unsigned int hi = f2bf(s * row[k + 1]);
  *(unsigned int*)&Wgb[h * 1024 + k] = lo | (hi << 16);
  if (kp == 0) {
    float* a = auxw + h * 8;
    a[0] = 63.0f * bg[h];
    a[1] = row[1024];
    a[2] = row[1025];
    a[3] = W4[h];
    a[4] = W4[512 + h];
    a[5] = W5[h];
    a[6] = 0.0f; a[7] = 0.0f;
  }
}

__global__ __launch_bounds__(512, 4) void traffic_kernel(
    const float* __restrict__ locs, const float* __restrict__ states,
    const unsigned short* __restrict__ Wgb, const float* __restrict__ auxw,
    const float* __restrict__ b4, const float* __restrict__ b5,
    float* __restrict__ out)
{
  __shared__ unsigned short S[32 * 520];     // 32 state rows, bf16, +8 pad (33.3 KB)
  __shared__ unsigned short Am[64 * 72];     // adjacency, diag 0 (9.2 KB)
  __shared__ unsigned short scr[8][16 * 40]; // per-wave transpose scratch (10.2 KB)
  __shared__ float locs_s[128];
  __shared__ float msgd[128];
  __shared__ float red[8 * 64 * 3];          // 6 KB
  // total ~59.9 KB -> 2 blocks/CU (LDS); VGPR <=128 by launch_bounds(512,4)

  const int t = threadIdx.x;
  const int b = blockIdx.x;
  const int lane = t & 63;
  const int w = t >> 6;                      // 8 waves
  const int llo = lane & 15;
  const int lhi = lane >> 4;
  const int hw = w * 64;                     // wave's 64-row h-slice

  if (t < 128) locs_s[t] = locs[b * 128 + t];
  __syncthreads();

  // ---- Phase A: adjacency Am + msg_d (thread = (row i, 8-col strip)) ----
  {
    const int i = t >> 3;                    // 0..63
    const int j0 = (t & 7) * 8;              // 0..56
    const float xi = locs_s[2*i], yi = locs_s[2*i+1];
    float a[8]; float psum = 0.f;
#pragma unroll
    for (int q = 0; q < 8; ++q) {
      int j = j0 + q;
      float dx = xi - locs_s[2*j];
      float dy = yi - locs_s[2*j+1];
      a[q] = (dx*dx + dy*dy < 1.0f) ? 1.0f : 0.0f;
      psum += a[q];
    }
    psum += __shfl_xor(psum, 1);
    psum += __shfl_xor(psum, 2);
    psum += __shfl_xor(psum, 4);             // row degree incl. self
    const float inv = 1.0f / psum;
    float m0 = 0.f, m1 = 0.f;
#pragma unroll
    for (int q = 0; q < 8; ++q) {
      int j = j0 + q;
      float v = (j == i) ? 0.f : a[q] * inv; // zero diagonal AFTER normalize
      a[q] = v;
      m0 += v * (xi - locs_s[2*j]);
      m1 += v * (yi - locs_s[2*j+1]);
    }
    m0 += __shfl_xor(m0, 1); m0 += __shfl_xor(m0, 2); m0 += __shfl_xor(m0, 4);
    m1 += __shfl_xor(m1, 1); m1 += __shfl_xor(m1, 2); m1 += __shfl_xor(m1, 4);
    if ((t & 7) == 0) { msgd[2*i] = m0; msgd[2*i+1] = m1; }
    union { unsigned short h8[8]; uint4 v4; } pk;
#pragma unroll
    for (int q = 0; q < 8; ++q) pk.h8[q] = f2bf(a[q]);
    *(uint4*)&Am[i*72 + j0] = pk.v4;         // 144=16*9 -> 16B aligned
  }

  // ---- staging: 32 state rows (one half) f32 -> S bf16 ----
  auto stageS = [&](int half) {
    const float4* sb = (const float4*)(states + (size_t)b * 32768 + half * 16384);
#pragma unroll
    for (int it = 0; it < 8; ++it) {
      int id = it * 512 + t;
      int j = id >> 7;
      int f0 = (id & 127) * 4;
      float4 v = sb[id];
      us4 s4;
      s4.x = f2bf(v.x); s4.y = f2bf(v.y);
      s4.z = f2bf(v.z); s4.w = f2bf(v.w);
      *(us4*)&S[j * 520 + f0] = s4;
    }
  };

  f32x4 acc[4][4];        // pre^T accumulator [mt(h)][nt(i)] = 64 VGPRs
  bf16x8 afr_reg[4];      // U2 A-fragments for D' (16 VGPRs)
  unsigned short* sc = &scr[w][0];
  const size_t wb = (size_t)(hw + llo) * 1024 + lhi * 8;  // Wgb lane base

  // C1 chunk (1 mt): au = W2f(16 rows) x S-half; transpose -> afr_reg[m]
  auto c1_chunk = [&](int m) {
    f32x4 au[2];
    au[0] = f32x4{0.f,0.f,0.f,0.f};
    au[1] = f32x4{0.f,0.f,0.f,0.f};
#pragma unroll 4
    for (int ks = 0; ks < 16; ++ks) {
      bf16x8 afr = *(const bf16x8*)&Wgb[wb + (size_t)m*16384 + 512 + ks*32];
      bf16x8 bfr0 = *(const bf16x8*)&S[(llo)*520 + ks*32 + lhi*8];
      bf16x8 bfr1 = *(const bf16x8*)&S[(16 + llo)*520 + ks*32 + lhi*8];
      au[0] = __builtin_amdgcn_mfma_f32_16x16x32_bf16(afr, bfr0, au[0], 0, 0, 0);
      au[1] = __builtin_amdgcn_mfma_f32_16x16x32_bf16(afr, bfr1, au[1], 0, 0, 0);
    }
    // transpose: C-layout (row=lhi*4+r, col=llo) -> A-frag (row=llo, k=lhi*8..)
#pragma unroll
    for (int n = 0; n < 2; ++n)
#pragma unroll
      for (int r = 0; r < 4; ++r)
        sc[(lhi*4 + r)*40 + n*16 + llo] = f2bf(au[n][r]);
    // same-wave in-order DS pipe: reads see prior writes (validated pattern)
    afr_reg[m] = *(const bf16x8*)&sc[llo*40 + lhi*8];
  };

  // D': acc += U2(regs) x Am(cols half*32..+31), K=32
  auto dprime = [&](int half) {
#pragma unroll
    for (int nt = 0; nt < 4; ++nt) {
      bf16x8 bfr = *(const bf16x8*)&Am[(nt*16 + llo)*72 + half*32 + lhi*8];
#pragma unroll
      for (int mt = 0; mt < 4; ++mt)
        acc[mt][nt] = __builtin_amdgcn_mfma_f32_16x16x32_bf16(afr_reg[mt], bfr, acc[mt][nt], 0, 0, 0);
    }
  };

  // C2 half: acc[:, half*2+n] += 63W1 x S-half (full K=512)
  auto c2_half = [&](int half) {
#pragma unroll 2
    for (int ks = 0; ks < 16; ++ks) {
      bf16x8 afr[4], bfr[2];
#pragma unroll
      for (int mt = 0; mt < 4; ++mt)
        afr[mt] = *(const bf16x8*)&Wgb[wb + (size_t)mt*16384 + ks*32];
#pragma unroll
      for (int n = 0; n < 2; ++n)
        bfr[n] = *(const bf16x8*)&S[(n*16 + llo)*520 + ks*32 + lhi*8];
#pragma unroll
      for (int mt = 0; mt < 4; ++mt)
#pragma unroll
        for (int n = 0; n < 2; ++n)
          acc[mt][half*2 + n] = __builtin_amdgcn_mfma_f32_16x16x32_bf16(afr[mt], bfr[n], acc[mt][half*2 + n], 0, 0, 0);
    }
  };

  // ---- half 0 (state rows 0..31) ----
  stageS(0);
  __syncthreads();
  c1_chunk(0); c1_chunk(1); c1_chunk(2); c1_chunk(3);
#pragma unroll
  for (int mt = 0; mt < 4; ++mt)
#pragma unroll
    for (int nt = 0; nt < 4; ++nt) acc[mt][nt] = f32x4{0.f,0.f,0.f,0.f};
  dprime(0);
  c2_half(0);
  __syncthreads();                 // all waves done with S half 0

  // ---- half 1 (state rows 32..63) ----
  stageS(1);
  __syncthreads();
  c1_chunk(0); c1_chunk(1); c1_chunk(2); c1_chunk(3);
  dprime(1);
  c2_half(1);

  // ---- epilogue: + msg_d@W2d + 63bg, relu, project W4/W5 ----
  float mdx[4], mdy[4];
#pragma unroll
  for (int nt = 0; nt < 4; ++nt) {
    mdx[nt] = msgd[2*(nt*16 + llo)];
    mdy[nt] = msgd[2*(nt*16 + llo) + 1];
  }
  float pp0[4] = {0,0,0,0}, pp1[4] = {0,0,0,0}, vv[4] = {0,0,0,0};
#pragma unroll
  for (int mt = 0; mt < 4; ++mt) {
#pragma unroll
    for (int r = 0; r < 4; ++r) {
      int hh = hw + mt*16 + lhi*4 + r;
      float4 ax0 = *(const float4*)&auxw[hh*8];      // {63bg, W2d0, W2d1, W4_0}
      float4 ax1 = *(const float4*)&auxw[hh*8 + 4];  // {W4_1, W5, 0, 0}
#pragma unroll
      for (int nt = 0; nt < 4; ++nt) {
        float val = acc[mt][nt][r] + ax0.x + mdx[nt]*ax0.y + mdy[nt]*ax0.z;
        val = fmaxf(val, 0.f);
        pp0[nt] += val * ax0.w;
        pp1[nt] += val * ax1.x;
        vv[nt]  += val * ax1.y;
      }
    }
  }
#pragma unroll
  for (int nt = 0; nt < 4; ++nt) {   // reduce over the 4 lhi groups
    pp0[nt] += __shfl_xor(pp0[nt], 16); pp0[nt] += __shfl_xor(pp0[nt], 32);
    pp1[nt] += __shfl_xor(pp1[nt], 16); pp1[nt] += __shfl_xor(pp1[nt], 32);
    vv[nt]  += __shfl_xor(vv[nt], 16);  vv[nt]  += __shfl_xor(vv[nt], 32);
  }
  if (lane < 16) {
#pragma unroll
    for (int nt = 0; nt < 4; ++nt) {
      int i = nt*16 + llo;
      red[(w*64 + i)*3 + 0] = pp0[nt];
      red[(w*64 + i)*3 + 1] = pp1[nt];
      red[(w*64 + i)*3 + 2] = vv[nt];
    }
  }
  __syncthreads();
  if (t < 192) {                     // cross-wave reduce + bias + store
    int o = t >> 6;                  // 0,1 -> policies; 2 -> values
    int i = t & 63;
    float s = 0.f;
#pragma unroll
    for (int ww = 0; ww < 8; ++ww) s += red[(ww*64 + i)*3 + o];
    s += (o < 2) ? b4[o] : b5[0];
    if (o < 2) out[((size_t)b*64 + i)*2 + o] = s;
    else       out[(size_t)131072 + (size_t)b*64 + i] = s;
  }
}

extern "C" void kernel_launch(void* const* d_in, const int* in_sizes, int n_in,
                              void* d_out, int out_size, void* d_ws, size_t ws_size,
                              hipStream_t stream)
{
  const float* locs   = (const float*)d_in[0];
  const float* states = (const float*)d_in[1];
  const float* Wg     = (const float*)d_in[2];
  const float* bg     = (const float*)d_in[3];
  const float* W4     = (const float*)d_in[4];
  const float* b4     = (const float*)d_in[5];
  const float* W5     = (const float*)d_in[6];
  const float* b5     = (const float*)d_in[7];

  unsigned short* Wgb = (unsigned short*)d_ws;                   // 1 MB bf16 weights
  float* auxw = (float*)((char*)d_ws + 512 * 1024 * 2);          // 16 KB epilogue table

  prep_kernel<<<1024, 256, 0, stream>>>(Wg, bg, W4, W5, Wgb, auxw);
  traffic_kernel<<<1024, 512, 0, stream>>>(locs, states, Wgb, auxw, b4, b5, (float*)d_out);
}